// Round 1
// baseline (68.661 us; speedup 1.0000x reference)
//
#include <hip/hip_runtime.h>
#include <hip/hip_bf16.h>

#define DDIM 4096
#define NROWS 16384
#define SK_ITERS 20

typedef __attribute__((ext_vector_type(8))) __bf16 bf16x8;
typedef __attribute__((ext_vector_type(4))) float f32x4;

// One block = one 16-row M-tile. 4 waves split K (1024 each).
// A (x rows) and B (W rows) fragments are loaded straight from global with the
// SAME (lane-quarter, elem)->k mapping: k = kbase + 8*(lane>>4) + i. Any
// consistent k-bijection gives a correct contraction; only row/col = lane&15
// and the verified C layout (col=lane&15, row=(lane>>4)*4+reg) matter.
__global__ __launch_bounds__(256, 4)
void rsm_kernel(const float* __restrict__ x, const float* __restrict__ W,
                const float* __restrict__ bias, const float* __restrict__ alpha_p,
                float* __restrict__ out)
{
    const int tile = blockIdx.x;
    const int tid  = threadIdx.x;
    const int wave = tid >> 6;   // K-quarter, and later the C-reg this wave finishes
    const int lane = tid & 63;
    const int r16  = lane & 15;  // A row-in-tile, B col (n), C col
    const int kq   = lane >> 4;  // lane quarter

    const float* xp0 = x + (size_t)(tile * 16 + r16) * DDIM + wave * 1024 + kq * 8;
    const float* wp0 = W + (size_t)r16 * DDIM + wave * 1024 + kq * 8;

    f32x4 acc = {0.f, 0.f, 0.f, 0.f};
    float sumsq = 0.f;

    #pragma unroll 4
    for (int s = 0; s < 32; ++s) {
        float4 a0 = *(const float4*)(xp0 + s * 32);
        float4 a1 = *(const float4*)(xp0 + s * 32 + 4);
        float4 b0 = *(const float4*)(wp0 + s * 32);
        float4 b1 = *(const float4*)(wp0 + s * 32 + 4);

        sumsq += a0.x * a0.x + a0.y * a0.y + a0.z * a0.z + a0.w * a0.w;
        sumsq += a1.x * a1.x + a1.y * a1.y + a1.z * a1.z + a1.w * a1.w;

        bf16x8 af, bfv;
        af[0] = (__bf16)a0.x; af[1] = (__bf16)a0.y; af[2] = (__bf16)a0.z; af[3] = (__bf16)a0.w;
        af[4] = (__bf16)a1.x; af[5] = (__bf16)a1.y; af[6] = (__bf16)a1.z; af[7] = (__bf16)a1.w;
        bfv[0] = (__bf16)b0.x; bfv[1] = (__bf16)b0.y; bfv[2] = (__bf16)b0.z; bfv[3] = (__bf16)b0.w;
        bfv[4] = (__bf16)b1.x; bfv[5] = (__bf16)b1.y; bfv[6] = (__bf16)b1.z; bfv[7] = (__bf16)b1.w;

        acc = __builtin_amdgcn_mfma_f32_16x16x32_bf16(af, bfv, acc, 0, 0, 0);
    }

    // Combine K-partials across the 4 waves via LDS.
    __shared__ __align__(16) float cpart[4][64][4];
    __shared__ float sqpart[4][64];
    *(f32x4*)(&cpart[wave][lane][0]) = acc;
    sqpart[wave][lane] = sumsq;
    __syncthreads();

    // Wave w finishes C-register r = w (token rows (lane>>4)*4 + w).
    float c = cpart[0][lane][wave] + cpart[1][lane][wave]
            + cpart[2][lane][wave] + cpart[3][lane][wave];

    // Full per-row sum of squares: sum the 4 wave-partials, then fold the
    // 4 lane-copies (bits 4,5). Every lane then holds S[lane&15].
    float s = sqpart[0][lane] + sqpart[1][lane]
            + sqpart[2][lane] + sqpart[3][lane];
    s += __shfl_xor(s, 16);
    s += __shfl_xor(s, 32);

    const int crow = kq * 4 + wave;       // token row of this lane's C element
    float Srow = __shfl(s, crow);         // lanes 0..15 hold S[0..15]
    float scale = rsqrtf(Srow * (1.0f / DDIM) + 1.1920929e-07f);  // fp32 eps

    float h = alpha_p[0] * (c * scale) + bias[r16];
    float m = expf(h);

    // Sinkhorn on the 4x4 living across the 16-lane group: n = i*4 + j,
    // col-sum over i -> xor {4,8}; row-sum over j -> xor {1,2}.
    for (int it = 0; it < SK_ITERS; ++it) {
        float t = m + __shfl_xor(m, 4);
        t += __shfl_xor(t, 8);
        m = m / (t + 1e-8f);
        t = m + __shfl_xor(m, 1);
        t += __shfl_xor(t, 2);
        m = m / (t + 1e-8f);
    }

    out[(size_t)(tile * 16 + crow) * 16 + r16] = m;
}

extern "C" void kernel_launch(void* const* d_in, const int* in_sizes, int n_in,
                              void* d_out, int out_size, void* d_ws, size_t ws_size,
                              hipStream_t stream) {
    const float* x     = (const float*)d_in[0];
    const float* W     = (const float*)d_in[1];
    const float* bias  = (const float*)d_in[2];
    const float* alpha = (const float*)d_in[3];
    float* out = (float*)d_out;

    rsm_kernel<<<dim3(NROWS / 16), dim3(256), 0, stream>>>(x, W, bias, alpha, out);
}

// Round 2
// 67.462 us; speedup vs baseline: 1.0178x; 1.0178x over previous
//
#include <hip/hip_runtime.h>
#include <hip/hip_bf16.h>

#define DDIM 4096
#define NROWS 16384
#define SK_ITERS 20
#define BK 256          // floats per K-chunk (per row)
#define NCHUNK 16       // DDIM / BK

typedef __attribute__((ext_vector_type(8))) __bf16 bf16x8;
typedef __attribute__((ext_vector_type(4))) float f32x4;

// Block = one 16-row tile, 4 waves. x is staged global->LDS via async DMA
// (global_load_lds, 16B/lane) double-buffered in BK=256 chunks; W read as
// plain float4 (L2-resident). LDS is XOR-swizzled (granule ^= row&7) via
// pre-swizzled GLOBAL source addresses (linear DMA dest) + swizzled ds_read.
// A/B share the k-mapping k = c*256 + w*64 + st*32 + kq*8 + i, so the MFMA
// contraction is correct (any consistent k-bijection works).
__global__ __launch_bounds__(256, 4)
void rsm_kernel(const float* __restrict__ x, const float* __restrict__ W,
                const float* __restrict__ bias, const float* __restrict__ alpha_p,
                float* __restrict__ out)
{
    __shared__ __align__(16) float lds[2][16][BK];   // 2 x 16 KB

    const int tile = blockIdx.x;
    const int tid  = threadIdx.x;
    const int wave = tid >> 6;
    const int lane = tid & 63;
    const int r16  = lane & 15;   // A row-in-tile, W row (output col), C col
    const int kq   = lane >> 4;

    char* lds_c = (char*)&lds[0][0][0];

    // Staging geometry, call j = 0..3 per chunk: granule G = j*256 + tid,
    // LDS phys (row G>>6, col-granule G&63) <- global col-granule (G&63)^(row&7).
    const float* sbase[4];
#pragma unroll
    for (int j = 0; j < 4; ++j) {
        int G  = j * 256 + tid;
        int sr = G >> 6;
        int sg = (G & 63) ^ (sr & 7);
        sbase[j] = x + (size_t)(tile * 16 + sr) * DDIM + sg * 4;
    }

    const float* wbase = W + (size_t)r16 * DDIM + wave * 64 + kq * 8;

    f32x4 acc = {0.f, 0.f, 0.f, 0.f};
    float sumsq = 0.f;

    auto stage = [&](int c, int b) {
#pragma unroll
        for (int j = 0; j < 4; ++j) {
            __builtin_amdgcn_global_load_lds(
                (const __attribute__((address_space(1))) void*)(sbase[j] + c * BK),
                (__attribute__((address_space(3))) void*)
                    (lds_c + b * 16384 + (j * 256 + wave * 64) * 16),
                16, 0, 0);
        }
    };

    stage(0, 0);
    int buf = 0;
    for (int c = 0; c < NCHUNK; ++c) {
        if (c + 1 < NCHUNK) stage(c + 1, buf ^ 1);
        __syncthreads();   // drains vmcnt: chunk c (and c+1 issue) landed

        const char* abase = lds_c + buf * 16384 + r16 * (BK * 4);
        const int z = r16 & 7;
#pragma unroll
        for (int st = 0; st < 2; ++st) {
            const int L0 = wave * 16 + st * 8 + kq * 2;   // logical granule
            float4 a0 = *(const float4*)(abase + ((L0    ) ^ z) * 16);
            float4 a1 = *(const float4*)(abase + ((L0 + 1) ^ z) * 16);
            const float* wp = wbase + c * BK + st * 32;
            float4 b0 = *(const float4*)(wp);
            float4 b1 = *(const float4*)(wp + 4);

            sumsq += a0.x*a0.x + a0.y*a0.y + a0.z*a0.z + a0.w*a0.w
                   + a1.x*a1.x + a1.y*a1.y + a1.z*a1.z + a1.w*a1.w;

            bf16x8 af, bv;
            af[0]=(__bf16)a0.x; af[1]=(__bf16)a0.y; af[2]=(__bf16)a0.z; af[3]=(__bf16)a0.w;
            af[4]=(__bf16)a1.x; af[5]=(__bf16)a1.y; af[6]=(__bf16)a1.z; af[7]=(__bf16)a1.w;
            bv[0]=(__bf16)b0.x; bv[1]=(__bf16)b0.y; bv[2]=(__bf16)b0.z; bv[3]=(__bf16)b0.w;
            bv[4]=(__bf16)b1.x; bv[5]=(__bf16)b1.y; bv[6]=(__bf16)b1.z; bv[7]=(__bf16)b1.w;

            acc = __builtin_amdgcn_mfma_f32_16x16x32_bf16(af, bv, acc, 0, 0, 0);
        }
        __syncthreads();   // all waves done reading buf before it is re-staged
        buf ^= 1;
    }

    // ---- epilogue: combine K-partials, RMSNorm scale, Sinkhorn ----
    float (*cpart)[64][4] = (float (*)[64][4])lds_c;          // 4 KB (aliases staging buf)
    float (*sqpart)[64]   = (float (*)[64])(lds_c + 4096);    // 1 KB

    *(f32x4*)(&cpart[wave][lane][0]) = acc;
    sqpart[wave][lane] = sumsq;
    __syncthreads();

    // Wave w finishes C-register r = w (token rows (lane>>4)*4 + w).
    float cg = cpart[0][lane][wave] + cpart[1][lane][wave]
             + cpart[2][lane][wave] + cpart[3][lane][wave];

    float s = sqpart[0][lane] + sqpart[1][lane]
            + sqpart[2][lane] + sqpart[3][lane];
    s += __shfl_xor(s, 16);
    s += __shfl_xor(s, 32);

    const int crow = kq * 4 + wave;
    float Srow = __shfl(s, crow);
    float scale = rsqrtf(Srow * (1.0f / DDIM) + 1.1920929e-07f);  // fp32 eps

    float h = alpha_p[0] * (cg * scale) + bias[r16];
    float m = expf(h);

    // Sinkhorn on the 4x4 across each 16-lane group: n = i*4 + j,
    // col-sum over i -> xor {4,8}; row-sum over j -> xor {1,2}.
    for (int it = 0; it < SK_ITERS; ++it) {
        float t = m + __shfl_xor(m, 4);
        t += __shfl_xor(t, 8);
        m = m / (t + 1e-8f);
        t = m + __shfl_xor(m, 1);
        t += __shfl_xor(t, 2);
        m = m / (t + 1e-8f);
    }

    out[(size_t)(tile * 16 + crow) * 16 + r16] = m;
}

extern "C" void kernel_launch(void* const* d_in, const int* in_sizes, int n_in,
                              void* d_out, int out_size, void* d_ws, size_t ws_size,
                              hipStream_t stream) {
    const float* x     = (const float*)d_in[0];
    const float* W     = (const float*)d_in[1];
    const float* bias  = (const float*)d_in[2];
    const float* alpha = (const float*)d_in[3];
    float* out = (float*)d_out;

    rsm_kernel<<<dim3(NROWS / 16), dim3(256), 0, stream>>>(x, W, bias, alpha, out);
}

// Round 3
// 56.273 us; speedup vs baseline: 1.2201x; 1.1988x over previous
//
#include <hip/hip_runtime.h>
#include <hip/hip_bf16.h>

#define DDIM 4096
#define NROWS 16384
#define SK_ITERS 20
#define BKW 64      // K-floats per chunk per wave
#define NCH 16      // 1024 / BKW chunks per wave (K-quarter)

typedef __attribute__((ext_vector_type(8))) __bf16 bf16x8;
typedef __attribute__((ext_vector_type(4))) float f32x4;
typedef __attribute__((ext_vector_type(4))) int   i32x4;

// Prologue: W fp32 -> bf16 (row-major, same indexing) into d_ws.
__global__ void wconv_kernel(const float* __restrict__ W, __bf16* __restrict__ Wb) {
    int i = (blockIdx.x * 256 + threadIdx.x) * 4;
    float4 v = *(const float4*)(W + i);
    __bf16 o4[4] = {(__bf16)v.x, (__bf16)v.y, (__bf16)v.z, (__bf16)v.w};
    *(ushort4*)(Wb + i) = *(const ushort4*)o4;
}

// Block = one 16-row tile, 4 waves splitting K (1024 each).
// Main loop is BARRIER-FREE: each wave DMA-stages its own 16x64-float chunks
// into wave-private LDS (depth-3 prefetch, counted vmcnt), and W(bf16) is
// register-pipelined 3 chunks ahead via inline-asm loads sharing the same
// vmcnt FIFO (issue group = 2 W-loads + 4 DMA = 6 vm ops -> wait vmcnt(18)).
// XOR swizzle: LDS[row][gp] = global[row][gp ^ (row&7)] (pre-swizzled source,
// linear DMA dest, swizzled ds_read) -> 2-way bank aliasing only (free).
// k-bijection (shared by A and B): k = wave*1024 + c*64 + st*32 + kq*8 + i.
__global__ __launch_bounds__(256, 2)
void rsm_kernel(const float* __restrict__ x, const __bf16* __restrict__ Wb,
                const float* __restrict__ bias, const float* __restrict__ alpha_p,
                float* __restrict__ out)
{
    __shared__ __align__(16) float lds[4][4][16][BKW];   // [wave][buf][row][k] = 64 KB

    const int tile = blockIdx.x;
    const int tid  = threadIdx.x;
    const int wave = tid >> 6;
    const int lane = tid & 63;
    const int r16  = lane & 15;   // A row-in-tile, W row (output col), C col
    const int kq   = lane >> 4;
    const int z    = r16 & 7;

    // DMA source bases: instr j stages granule G = j*64 + lane:
    // row = G>>4, LDS phys granule gp = G&15, global granule = gp ^ (row&7).
    const float* sbase[4];
#pragma unroll
    for (int j = 0; j < 4; ++j) {
        int G  = j * 64 + lane;
        int sr = G >> 4;
        int sg = (G & 15) ^ (sr & 7);
        sbase[j] = x + (size_t)(tile * 16 + sr) * DDIM + wave * 1024 + sg * 4;
    }

    const __bf16* wqb = Wb + (size_t)r16 * DDIM + wave * 1024 + kq * 8;

    i32x4 wb[4][2];   // W bf16 register pipeline (indices constant after unroll)

    auto wissue = [&](int g) {
        asm volatile("global_load_dwordx4 %0, %2, off\n\t"
                     "global_load_dwordx4 %1, %3, off"
                     : "=&v"(wb[g & 3][0]), "=&v"(wb[g & 3][1])
                     : "v"(wqb + g * 64), "v"(wqb + g * 64 + 32));
    };

    auto stage = [&](int c) {
        int b = c & 3;
#pragma unroll
        for (int j = 0; j < 4; ++j) {
            __builtin_amdgcn_global_load_lds(
                (const __attribute__((address_space(1))) void*)(sbase[j] + c * BKW),
                (__attribute__((address_space(3))) void*)(&lds[wave][b][0][0] + j * 256),
                16, 0, 0);
        }
    };

    wissue(0); stage(0);
    wissue(1); stage(1);
    wissue(2); stage(2);

    f32x4 acc = {0.f, 0.f, 0.f, 0.f};
    float sumsq = 0.f;

#pragma unroll
    for (int c = 0; c < NCH; ++c) {
        if (c + 3 < NCH) { wissue(c + 3); stage(c + 3); }
        __builtin_amdgcn_sched_barrier(0);
        if (c <= NCH - 4)      asm volatile("s_waitcnt vmcnt(18)" ::: "memory");
        else if (c == NCH - 3) asm volatile("s_waitcnt vmcnt(12)" ::: "memory");
        else if (c == NCH - 2) asm volatile("s_waitcnt vmcnt(6)"  ::: "memory");
        else                   asm volatile("s_waitcnt vmcnt(0)"  ::: "memory");
        __builtin_amdgcn_sched_barrier(0);

        const float* arow = &lds[wave][c & 3][r16][0];
#pragma unroll
        for (int st = 0; st < 2; ++st) {
            int L0 = st * 8 + kq * 2;
            float4 a0 = *(const float4*)(arow + (((L0    ) ^ z) << 2));
            float4 a1 = *(const float4*)(arow + (((L0 + 1) ^ z) << 2));

            sumsq += a0.x*a0.x + a0.y*a0.y + a0.z*a0.z + a0.w*a0.w
                   + a1.x*a1.x + a1.y*a1.y + a1.z*a1.z + a1.w*a1.w;

            bf16x8 af;
            af[0]=(__bf16)a0.x; af[1]=(__bf16)a0.y; af[2]=(__bf16)a0.z; af[3]=(__bf16)a0.w;
            af[4]=(__bf16)a1.x; af[5]=(__bf16)a1.y; af[6]=(__bf16)a1.z; af[7]=(__bf16)a1.w;
            bf16x8 bv = __builtin_bit_cast(bf16x8, wb[c & 3][st]);

            acc = __builtin_amdgcn_mfma_f32_16x16x32_bf16(af, bv, acc, 0, 0, 0);
        }
    }

    // ---- epilogue: combine K-partials, RMSNorm scale, Sinkhorn ----
    __syncthreads();   // drains all counters; safe to reuse LDS
    float (*cpart)[64][4] = (float (*)[64][4])&lds[0][0][0][0];          // 4 KB
    float (*sqpart)[64]   = (float (*)[64])((char*)&lds[0][0][0][0] + 4096);

    *(f32x4*)(&cpart[wave][lane][0]) = acc;
    sqpart[wave][lane] = sumsq;
    __syncthreads();

    // Wave w finishes C-register r = w (token rows (lane>>4)*4 + w).
    float cg = cpart[0][lane][wave] + cpart[1][lane][wave]
             + cpart[2][lane][wave] + cpart[3][lane][wave];

    float s = sqpart[0][lane] + sqpart[1][lane]
            + sqpart[2][lane] + sqpart[3][lane];
    s += __shfl_xor(s, 16);
    s += __shfl_xor(s, 32);

    const int crow = kq * 4 + wave;
    float Srow = __shfl(s, crow);
    float scale = rsqrtf(Srow * (1.0f / DDIM) + 1.1920929e-07f);  // fp32 eps

    float h = alpha_p[0] * (cg * scale) + bias[r16];
    float m = expf(h);

    // Sinkhorn on the 4x4 across each 16-lane group: n = i*4 + j,
    // col-sum over i -> xor {4,8}; row-sum over j -> xor {1,2}.
    for (int it = 0; it < SK_ITERS; ++it) {
        float t = m + __shfl_xor(m, 4);
        t += __shfl_xor(t, 8);
        m = m / (t + 1e-8f);
        t = m + __shfl_xor(m, 1);
        t += __shfl_xor(t, 2);
        m = m / (t + 1e-8f);
    }

    out[(size_t)(tile * 16 + crow) * 16 + r16] = m;
}

extern "C" void kernel_launch(void* const* d_in, const int* in_sizes, int n_in,
                              void* d_out, int out_size, void* d_ws, size_t ws_size,
                              hipStream_t stream) {
    const float* x     = (const float*)d_in[0];
    const float* W     = (const float*)d_in[1];
    const float* bias  = (const float*)d_in[2];
    const float* alpha = (const float*)d_in[3];
    float* out = (float*)d_out;
    __bf16* Wb = (__bf16*)d_ws;   // 16*4096*2 = 128 KB scratch

    wconv_kernel<<<dim3(64), dim3(256), 0, stream>>>(W, Wb);
    rsm_kernel<<<dim3(NROWS / 16), dim3(256), 0, stream>>>(x, Wb, bias, alpha, out);
}